// Round 1
// 184.089 us; speedup vs baseline: 1.0506x; 1.0506x over previous
//
#include <hip/hip_runtime.h>
#include <hip/hip_bf16.h>
#include <cstdint>

// MxDNA deformable conv block, MI355X/gfx950.
// K1: per-token tap coefficients; K2: W repack to bf16 [d][k*256+e];
// K3: fused gather-lerp + bf16 MFMA GEMM (M=65536, N=256, Kred=768).
// Round 4: double-buffered LDS (1 barrier/iter), per-thread coef registers,
// register prefetch distance 2 for global loads.
// Round 5: XCD-aware bijective block swizzle in K3. HW round-robins blocks
// across the 8 non-coherent XCD L2s, so the ntile pair of each mtile was
// fetching the same x rows on two XCDs (x fetched 2x = 128 MB) and the
// doubled stream thrashed WB out of L2 (~70 MB re-fetch). Remap so
// xcd = b&7 owns exactly batch xcd: both ntiles co-located, x 8 MB/XCD.

#define N_TOK 8192
#define DIM   256
#define KW    768        // reduction length K*D
#define BM    128
#define BN    128
#define BK    32

typedef unsigned short u16;
typedef __attribute__((ext_vector_type(4))) float    floatx4;
typedef __attribute__((ext_vector_type(8))) __bf16   bf16x8;
typedef __attribute__((ext_vector_type(8))) u16      ushortx8;

__device__ __forceinline__ u16 f32_to_bf16_rne(float f) {
    uint32_t u = __float_as_uint(f);
    u += 0x7fffu + ((u >> 16) & 1u);
    return (u16)(u >> 16);
}

// ---------------- Kernel 1: per-token coefficients ----------------
__global__ __launch_bounds__(256) void coef_kernel(
    const float* __restrict__ x, const float* __restrict__ offw,
    const float* __restrict__ modw, int4* __restrict__ coef)
{
    const int wave = threadIdx.x >> 6;
    const int lane = threadIdx.x & 63;
    const int t = blockIdx.x * 4 + wave;

    const float4 xv = ((const float4*)(x + (size_t)t * DIM))[lane];
    float s[6];
#pragma unroll
    for (int k = 0; k < 3; ++k) {
        float4 wv = ((const float4*)(offw + k * DIM))[lane];
        s[k]     = xv.x * wv.x + xv.y * wv.y + xv.z * wv.z + xv.w * wv.w;
        float4 mv = ((const float4*)(modw + k * DIM))[lane];
        s[3 + k] = xv.x * mv.x + xv.y * mv.y + xv.z * mv.z + xv.w * mv.w;
    }
#pragma unroll
    for (int d = 1; d < 64; d <<= 1) {
#pragma unroll
        for (int i = 0; i < 6; ++i) s[i] += __shfl_xor(s[i], d, 64);
    }
    if (lane < 3) {
        const int k = lane;
        const int n = t & (N_TOK - 1);
        float pos   = (float)(n + k - 1) + s[k];
        bool  valid = (pos >= 0.0f) && (pos < (float)N_TOK);
        float ff = floorf(pos);
        ff = fminf(fmaxf(ff, 0.0f), (float)(N_TOK - 1));
        int   fi = (int)ff;
        int   ci = min(fi + 1, N_TOK - 1);
        float wc = pos - ff;
        float m  = valid ? (1.0f / (1.0f + expf(-s[3 + k]))) : 0.0f;
        coef[t * 3 + k] = make_int4(fi, ci,
                                    __float_as_int((1.0f - wc) * m),
                                    __float_as_int(wc * m));
    }
}

// ---------------- Kernel 2: repack weight to bf16 WB[d][k*256+e] ----------------
__global__ __launch_bounds__(256) void packw_kernel(
    const float* __restrict__ W, u16* __restrict__ WB)
{
    const int d = blockIdx.x;
    const int e = threadIdx.x;
#pragma unroll
    for (int k = 0; k < 3; ++k)
        WB[d * KW + k * DIM + e] = f32_to_bf16_rne(W[d * KW + e * 3 + k]);
}

// ---------------- Kernel 3: fused gather/lerp + MFMA GEMM, dbuf pipeline ----------------
// block = 256 thr (4 waves), tile 128(M) x 128(N), BK=32, 24 K-iters.
// LDS rows padded to 40 shorts (80 B): 16-lane b128 reads are 2-way (free).
// Double buffer: iter kk reads buf[kk&1], writes buf[kk&1 ^ 1]; single
// end-of-iter barrier separates both cross-iteration hazards.
__global__ __launch_bounds__(256) void deform_gemm_kernel(
    const float* __restrict__ x, const u16* __restrict__ WB,
    const int4* __restrict__ coef, float* __restrict__ out)
{
    __shared__ __align__(16) u16 As[2][BM * 40];   // 2 x 10240 B
    __shared__ __align__(16) u16 Bs[2][BN * 40];   // 2 x 10240 B

    const int tid  = threadIdx.x;
    const int wave = tid >> 6;
    const int lane = tid & 63;

    // XCD-aware bijective swizzle: 1024 blocks, 8 XCDs (hw: xcd = b % 8).
    // XCD x owns mtiles [x*64, (x+1)*64) == batch x; both ntiles of an
    // mtile land on the same XCD, adjacent in dispatch order.
    const int raw   = blockIdx.x;
    const int xcd   = raw & 7;
    const int lidx  = raw >> 3;                  // 0..127 within XCD
    const int mtile = xcd * ((65536 / BM) / 8) + (lidx >> 1);
    const int ntile = lidx & 1;

    const int t0 = mtile * BM;
    const int n0 = ntile * BN;
    const float* xb = x + (size_t)(t0 / N_TOK) * N_TOK * DIM;  // batch base (BM | N_TOK)

    const int tl = tid >> 1;         // token-local 0..127
    const int eh = tid & 1;          // 16-column half
    const int wm = (wave & 1) * 64;  // wave quadrant in M
    const int wn = (wave >> 1) * 64; // wave quadrant in N
    const int lrow = lane & 15;
    const int lq   = lane >> 4;

    // per-thread coefficients for token t0+tl (3 taps) — registers, no LDS
    const int4 cc0 = coef[(size_t)(t0 + tl) * 3 + 0];
    const int4 cc1 = coef[(size_t)(t0 + tl) * 3 + 1];
    const int4 cc2 = coef[(size_t)(t0 + tl) * 3 + 2];

    // prefetch registers (slice kk's data; consumed by packstore, then refilled)
    float4 pf[4], pc[4];
    uint4  pb0, pb1;
    float  wA, wC;

    auto loadg = [&](int kk) {
        const int tap = kk >> 3;
        const int4 c = (tap == 0) ? cc0 : (tap == 1 ? cc1 : cc2);
        const int e0 = (kk & 7) * 32 + eh * 16;
        wA = __int_as_float(c.z);
        wC = __int_as_float(c.w);
        const float4* rowf = (const float4*)(xb + (size_t)c.x * DIM + e0);
        const float4* rowc = (const float4*)(xb + (size_t)c.y * DIM + e0);
#pragma unroll
        for (int j = 0; j < 4; ++j) { pf[j] = rowf[j]; pc[j] = rowc[j]; }
        const uint4* g = (const uint4*)(WB + (size_t)(n0 + tl) * KW + kk * BK + eh * 16);
        pb0 = g[0];
        pb1 = g[1];
    };

    auto packstore = [&](int buf) {
        uint32_t p[8];
#pragma unroll
        for (int j = 0; j < 4; ++j) {
            float r0 = wA * pf[j].x + wC * pc[j].x;
            float r1 = wA * pf[j].y + wC * pc[j].y;
            float r2 = wA * pf[j].z + wC * pc[j].z;
            float r3 = wA * pf[j].w + wC * pc[j].w;
            p[j * 2 + 0] = __builtin_amdgcn_perm(__float_as_uint(r1), __float_as_uint(r0), 0x07060302u);
            p[j * 2 + 1] = __builtin_amdgcn_perm(__float_as_uint(r3), __float_as_uint(r2), 0x07060302u);
        }
        uint4* adst = (uint4*)&As[buf][tl * 40 + eh * 16];
        adst[0] = make_uint4(p[0], p[1], p[2], p[3]);
        adst[1] = make_uint4(p[4], p[5], p[6], p[7]);
        uint4* bdst = (uint4*)&Bs[buf][tl * 40 + eh * 16];
        bdst[0] = pb0;
        bdst[1] = pb1;
    };

    // prologue: slice 0 -> buf0; prefetch slice 1 into registers
    loadg(0);
    packstore(0);
    loadg(1);

    floatx4 acc[4][4];
#pragma unroll
    for (int i = 0; i < 4; ++i)
#pragma unroll
        for (int j = 0; j < 4; ++j) acc[i][j] = (floatx4){0.f, 0.f, 0.f, 0.f};

    __syncthreads();                 // buf0 visible

    for (int kk = 0; kk < 24; ++kk) {
        const int cur = kk & 1;
        // fragments for slice kk from buf[cur]
        bf16x8 af[4], bfv[4];
#pragma unroll
        for (int i = 0; i < 4; ++i)
            af[i] = __builtin_bit_cast(bf16x8, *(const ushortx8*)&As[cur][(wm + i * 16 + lrow) * 40 + lq * 8]);
#pragma unroll
        for (int j = 0; j < 4; ++j)
            bfv[j] = __builtin_bit_cast(bf16x8, *(const ushortx8*)&Bs[cur][(wn + j * 16 + lrow) * 40 + lq * 8]);
        // stage slice kk+1 into the OTHER buffer (no conflict with this iter's reads)
        if (kk < 23) packstore(cur ^ 1);
        // refill prefetch registers with slice kk+2
        if (kk < 22) loadg(kk + 2);
#pragma unroll
        for (int i = 0; i < 4; ++i)
#pragma unroll
            for (int j = 0; j < 4; ++j)
                acc[i][j] = __builtin_amdgcn_mfma_f32_16x16x32_bf16(af[i], bfv[j], acc[i][j], 0, 0, 0);
        __syncthreads();             // separates writes(kk)->reads(kk+1) and reads(kk)->writes(kk+1)
    }

    // ---- epilogue: C/D layout col = lane&15, row = (lane>>4)*4 + reg
#pragma unroll
    for (int i = 0; i < 4; ++i) {
#pragma unroll
        for (int r = 0; r < 4; ++r) {
            const int token = t0 + wm + i * 16 + lq * 4 + r;
            float* op = out + (size_t)token * DIM + n0 + wn + lrow;
#pragma unroll
            for (int j = 0; j < 4; ++j) op[j * 16] = acc[i][j][r];
        }
    }
}

extern "C" void kernel_launch(void* const* d_in, const int* in_sizes, int n_in,
                              void* d_out, int out_size, void* d_ws, size_t ws_size,
                              hipStream_t stream)
{
    const float* x    = (const float*)d_in[0];  // (8, 8192, 256)
    const float* offw = (const float*)d_in[1];  // (3, 256)
    const float* modw = (const float*)d_in[2];  // (3, 256)
    const float* W    = (const float*)d_in[3];  // (256, 256, 3)
    float* out = (float*)d_out;                 // (8, 8192, 256)

    const int tot_tok = 8 * N_TOK;              // 65536
    int4* coef = (int4*)d_ws;                                       // 3,145,728 B
    u16*  WB   = (u16*)((char*)d_ws + (size_t)tot_tok * 3 * 16);    //   393,216 B

    coef_kernel<<<tot_tok / 4, 256, 0, stream>>>(x, offw, modw, coef);
    packw_kernel<<<DIM, 256, 0, stream>>>(W, WB);
    deform_gemm_kernel<<<(tot_tok / BM) * (DIM / BN), 256, 0, stream>>>(x, WB, coef, out);
}

// Round 2
// 176.779 us; speedup vs baseline: 1.0940x; 1.0413x over previous
//
#include <hip/hip_runtime.h>
#include <hip/hip_bf16.h>
#include <cstdint>

// MxDNA deformable conv block, MI355X/gfx950.
// K1: per-token tap coefficients; K2: W repack to bf16 [d][k*256+e];
// K3: fused gather-lerp + bf16 MFMA GEMM (M=65536, N=256, Kred=768).
// Round 4: double-buffered LDS (1 barrier/iter), reg prefetch distance 2.
// Round 5: XCD-aware bijective block swizzle (FETCH 203->69 MB).
// Round 6: occupancy attack. Old shape (BM=BN=128, 4 waves, acc 4x4=64 AGPR,
// 116 arch VGPR -> ~180 unified regs) capped residency at 8 waves/CU; all
// pipes idle (Mfma 13%, VALU 15%, HBM 23%). New shape: BM=64 x BN=256
// (full N per block -> each token gathered/lerped ONCE, not per-ntile),
// 512 thr / 8 waves, wave tile 32x64 -> acc 2x4 = 32 AGPR, lean staging,
// __launch_bounds__(512,4) forces <=128 regs -> 16 waves/CU (2 blocks).

#define N_TOK 8192
#define DIM   256
#define KW    768        // reduction length K*D
#define BM    64
#define BN    256
#define BK    32

typedef unsigned short u16;
typedef __attribute__((ext_vector_type(4))) float    floatx4;
typedef __attribute__((ext_vector_type(8))) __bf16   bf16x8;
typedef __attribute__((ext_vector_type(8))) u16      ushortx8;

__device__ __forceinline__ u16 f32_to_bf16_rne(float f) {
    uint32_t u = __float_as_uint(f);
    u += 0x7fffu + ((u >> 16) & 1u);
    return (u16)(u >> 16);
}

// ---------------- Kernel 1: per-token coefficients ----------------
__global__ __launch_bounds__(256) void coef_kernel(
    const float* __restrict__ x, const float* __restrict__ offw,
    const float* __restrict__ modw, int4* __restrict__ coef)
{
    const int wave = threadIdx.x >> 6;
    const int lane = threadIdx.x & 63;
    const int t = blockIdx.x * 4 + wave;

    const float4 xv = ((const float4*)(x + (size_t)t * DIM))[lane];
    float s[6];
#pragma unroll
    for (int k = 0; k < 3; ++k) {
        float4 wv = ((const float4*)(offw + k * DIM))[lane];
        s[k]     = xv.x * wv.x + xv.y * wv.y + xv.z * wv.z + xv.w * wv.w;
        float4 mv = ((const float4*)(modw + k * DIM))[lane];
        s[3 + k] = xv.x * mv.x + xv.y * mv.y + xv.z * mv.z + xv.w * mv.w;
    }
#pragma unroll
    for (int d = 1; d < 64; d <<= 1) {
#pragma unroll
        for (int i = 0; i < 6; ++i) s[i] += __shfl_xor(s[i], d, 64);
    }
    if (lane < 3) {
        const int k = lane;
        const int n = t & (N_TOK - 1);
        float pos   = (float)(n + k - 1) + s[k];
        bool  valid = (pos >= 0.0f) && (pos < (float)N_TOK);
        float ff = floorf(pos);
        ff = fminf(fmaxf(ff, 0.0f), (float)(N_TOK - 1));
        int   fi = (int)ff;
        int   ci = min(fi + 1, N_TOK - 1);
        float wc = pos - ff;
        float m  = valid ? (1.0f / (1.0f + expf(-s[3 + k]))) : 0.0f;
        coef[t * 3 + k] = make_int4(fi, ci,
                                    __float_as_int((1.0f - wc) * m),
                                    __float_as_int(wc * m));
    }
}

// ---------------- Kernel 2: repack weight to bf16 WB[d][k*256+e] ----------------
__global__ __launch_bounds__(256) void packw_kernel(
    const float* __restrict__ W, u16* __restrict__ WB)
{
    const int d = blockIdx.x;
    const int e = threadIdx.x;
#pragma unroll
    for (int k = 0; k < 3; ++k)
        WB[d * KW + k * DIM + e] = f32_to_bf16_rne(W[d * KW + e * 3 + k]);
}

// ---------------- Kernel 3: fused gather/lerp + MFMA GEMM, dbuf pipeline ----------------
// block = 512 thr (8 waves), tile 64(M) x 256(N), BK=32, 24 K-iters.
// Wave tile 32x64: acc 2x4 frags = 32 AGPR; staging 32 B x + 32 B WB per
// thread. LDS rows padded to 40 shorts (80 B). Double buffer, single
// end-of-iter barrier, register prefetch distance 2.
__global__ __launch_bounds__(512, 4) void deform_gemm_kernel(
    const float* __restrict__ x, const u16* __restrict__ WB,
    const int4* __restrict__ coef, float* __restrict__ out)
{
    __shared__ __align__(16) u16 As[2][BM * 40];   // 2 x  5120 B
    __shared__ __align__(16) u16 Bs[2][BN * 40];   // 2 x 20480 B

    const int tid  = threadIdx.x;
    const int wave = tid >> 6;
    const int lane = tid & 63;

    // XCD-aware bijective swizzle: 1024 blocks, hw xcd = b % 8.
    // XCD x owns mtiles [x*128, (x+1)*128) == batch x.
    const int raw   = blockIdx.x;
    const int xcd   = raw & 7;
    const int lidx  = raw >> 3;              // 0..127 within XCD
    const int mtile = xcd * 128 + lidx;
    const int t0 = mtile * BM;
    const float* xb = x + (size_t)(t0 / N_TOK) * N_TOK * DIM;  // batch base (BM | N_TOK)

    // A staging role: token tl (0..63), 4-float column segment sub (0..7)
    const int tl  = tid >> 3;
    const int sub = tid & 7;
    // B staging role: WB row br (0..255), 16-short half bh
    const int br = tid >> 1;
    const int bh = tid & 1;

    const int wm = (wave & 1) * 32;   // wave M quadrant (2)
    const int wn = (wave >> 1) * 64;  // wave N quadrant (4)
    const int lrow = lane & 15;
    const int lq   = lane >> 4;

    // per-thread coefficients for token t0+tl (3 taps) — registers
    const int4 cc0 = coef[(size_t)(t0 + tl) * 3 + 0];
    const int4 cc1 = coef[(size_t)(t0 + tl) * 3 + 1];
    const int4 cc2 = coef[(size_t)(t0 + tl) * 3 + 2];

    // prefetch registers (slice kk's data)
    float4 pf, pc;
    uint4  pb0, pb1;
    float  wA, wC;

    auto loadg = [&](int kk) {
        const int tap = kk >> 3;
        const int4 c = (tap == 0) ? cc0 : (tap == 1 ? cc1 : cc2);
        const int e0 = (kk & 7) * 32 + sub * 4;
        wA = __int_as_float(c.z);
        wC = __int_as_float(c.w);
        pf = *(const float4*)(xb + (size_t)c.x * DIM + e0);
        pc = *(const float4*)(xb + (size_t)c.y * DIM + e0);
        const uint4* g = (const uint4*)(WB + (size_t)br * KW + kk * BK + bh * 16);
        pb0 = g[0];
        pb1 = g[1];
    };

    auto packstore = [&](int buf) {
        float r0 = wA * pf.x + wC * pc.x;
        float r1 = wA * pf.y + wC * pc.y;
        float r2 = wA * pf.z + wC * pc.z;
        float r3 = wA * pf.w + wC * pc.w;
        uint32_t p0 = __builtin_amdgcn_perm(__float_as_uint(r1), __float_as_uint(r0), 0x07060302u);
        uint32_t p1 = __builtin_amdgcn_perm(__float_as_uint(r3), __float_as_uint(r2), 0x07060302u);
        *(uint2*)&As[buf][tl * 40 + sub * 4] = make_uint2(p0, p1);
        uint4* bdst = (uint4*)&Bs[buf][br * 40 + bh * 16];
        bdst[0] = pb0;
        bdst[1] = pb1;
    };

    // prologue: slice 0 -> buf0; prefetch slice 1 into registers
    loadg(0);
    packstore(0);
    loadg(1);

    floatx4 acc[2][4];
#pragma unroll
    for (int i = 0; i < 2; ++i)
#pragma unroll
        for (int j = 0; j < 4; ++j) acc[i][j] = (floatx4){0.f, 0.f, 0.f, 0.f};

    __syncthreads();                 // buf0 visible

    for (int kk = 0; kk < 24; ++kk) {
        const int cur = kk & 1;
        // fragments for slice kk from buf[cur]
        bf16x8 af[2], bfv[4];
#pragma unroll
        for (int i = 0; i < 2; ++i)
            af[i] = __builtin_bit_cast(bf16x8, *(const ushortx8*)&As[cur][(wm + i * 16 + lrow) * 40 + lq * 8]);
#pragma unroll
        for (int j = 0; j < 4; ++j)
            bfv[j] = __builtin_bit_cast(bf16x8, *(const ushortx8*)&Bs[cur][(wn + j * 16 + lrow) * 40 + lq * 8]);
        // stage slice kk+1 into the OTHER buffer
        if (kk < 23) packstore(cur ^ 1);
        // refill prefetch registers with slice kk+2
        if (kk < 22) loadg(kk + 2);
#pragma unroll
        for (int i = 0; i < 2; ++i)
#pragma unroll
            for (int j = 0; j < 4; ++j)
                acc[i][j] = __builtin_amdgcn_mfma_f32_16x16x32_bf16(af[i], bfv[j], acc[i][j], 0, 0, 0);
        __syncthreads();             // separates writes(kk)->reads(kk+1) and reads(kk)->writes(kk+1)
    }

    // ---- epilogue: C/D layout col = lane&15, row = (lane>>4)*4 + reg
#pragma unroll
    for (int i = 0; i < 2; ++i) {
#pragma unroll
        for (int r = 0; r < 4; ++r) {
            const int token = t0 + wm + i * 16 + lq * 4 + r;
            float* op = out + (size_t)token * DIM + wn + lrow;
#pragma unroll
            for (int j = 0; j < 4; ++j) op[j * 16] = acc[i][j][r];
        }
    }
}

extern "C" void kernel_launch(void* const* d_in, const int* in_sizes, int n_in,
                              void* d_out, int out_size, void* d_ws, size_t ws_size,
                              hipStream_t stream)
{
    const float* x    = (const float*)d_in[0];  // (8, 8192, 256)
    const float* offw = (const float*)d_in[1];  // (3, 256)
    const float* modw = (const float*)d_in[2];  // (3, 256)
    const float* W    = (const float*)d_in[3];  // (256, 256, 3)
    float* out = (float*)d_out;                 // (8, 8192, 256)

    const int tot_tok = 8 * N_TOK;              // 65536
    int4* coef = (int4*)d_ws;                                       // 3,145,728 B
    u16*  WB   = (u16*)((char*)d_ws + (size_t)tot_tok * 3 * 16);    //   393,216 B

    coef_kernel<<<tot_tok / 4, 256, 0, stream>>>(x, offw, modw, coef);
    packw_kernel<<<DIM, 256, 0, stream>>>(W, WB);
    deform_gemm_kernel<<<tot_tok / BM, 512, 0, stream>>>(x, WB, coef, out);
}